// Round 7
// baseline (211.068 us; speedup 1.0000x reference)
//
#include <hip/hip_runtime.h>
#include <cstdint>
#include <cstddef>

#define NC 64
#define EROW 36   // dwords per packed-E row in LDS (32 data + 4 pad; only used pre-loop)
#define LN2 0.6931471805599453f

typedef _Float16 half2_t __attribute__((ext_vector_type(2)));

static __device__ __forceinline__ float dot2acc(uint32_t a, uint32_t b, float c) {
#if __has_builtin(__builtin_amdgcn_fdot2)
    return __builtin_amdgcn_fdot2(__builtin_bit_cast(half2_t, a),
                                  __builtin_bit_cast(half2_t, b), c, false);
#else
    half2_t ha = __builtin_bit_cast(half2_t, a), hb = __builtin_bit_cast(half2_t, b);
    return c + (float)ha[0] * (float)hb[0] + (float)ha[1] * (float)hb[1];
#endif
}

template <int CTRL>
static __device__ __forceinline__ float dppf(float x) {
    return __int_as_float(__builtin_amdgcn_update_dpp(
        0, __float_as_int(x), CTRL, 0xf, 0xf, true));
}
static __device__ __forceinline__ float wave_sum_bcast(float x) {
    x = x + dppf<0x111>(x);
    x = x + dppf<0x112>(x);
    x = x + dppf<0x114>(x);
    x = x + dppf<0x118>(x);
    x = x + dppf<0x142>(x);   // row_bcast15
    x = x + dppf<0x143>(x);   // row_bcast31
    return __int_as_float(__builtin_amdgcn_readlane(__float_as_int(x), 63));
}

__global__ __launch_bounds__(64, 1)
void crf_nll_kernel(const float* __restrict__ logits,
                    const float* __restrict__ trans,
                    const float* __restrict__ init_alphas,
                    const int*  __restrict__ lengths,
                    const int*  __restrict__ tags,
                    float* __restrict__ out,
                    int N, int T)
{
    const int n = blockIdx.x;
    const int lane = threadIdx.x;              // 0..63, owns class row `lane`
    const float* lg = logits + (size_t)n * T * NC;
    const int len = lengths[n];                // in [2, T]
    const int Tm1 = T - 1;

    __shared__ __align__(16) uint32_t E_pk[64 * EROW];  // staging for exp(trans) f16x2
    __shared__ __align__(16) uint16_t v_pk[NC + 8];     // state, packed f16

    // ---- fill packed E in LDS: word (row,k) = {f16(e^tr[row][2k]), f16(e^tr[row][2k+1])}
    const float2* tr2 = reinterpret_cast<const float2*>(trans);
    #pragma unroll
    for (int i = lane; i < 64 * 32; i += 64) {
        int row = i >> 5, k = i & 31;
        float2 t2 = tr2[i];
        uint32_t lo = (uint32_t)__builtin_bit_cast(uint16_t, (_Float16)__expf(t2.x));
        uint32_t hi = (uint32_t)__builtin_bit_cast(uint16_t, (_Float16)__expf(t2.y));
        E_pk[row * EROW + k] = (hi << 16) | lo;
    }

    // ---- hoist this lane's E row into 8 named uint4 (32 VGPRs), ONCE.
    // Loaded from LDS (not recomputed from global) so the in-loop v_pk stores
    // make these non-rematerializable -> allocator must keep them resident.
    const uint4* Ebase = reinterpret_cast<const uint4*>(&E_pk[lane * EROW]);
    const uint4 e0 = Ebase[0], e1 = Ebase[1], e2 = Ebase[2], e3 = Ebase[3];
    const uint4 e4 = Ebase[4], e5 = Ebase[5], e6 = Ebase[6], e7 = Ebase[7];

    // ---- init: alpha0 = init + logits[0]; normalize so lane-0 value = 2^-4
    float a0 = init_alphas[lane] + lg[lane];
    float L  = __int_as_float(__builtin_amdgcn_readfirstlane(__float_as_int(a0)))
               + 4.f * LN2;                    // lane0: exp(a0 - L) = 1/16
    float vn = __expf(a0 - L);
    v_pk[lane] = __builtin_bit_cast(uint16_t, (_Float16)vn);
    // single wave: DS pipe is in-order; no barrier needed anywhere

    const uint4* vb4 = reinterpret_cast<const uint4*>(v_pk);

    // one alpha-recursion step given the raw logit value for this row
    auto step = [&](float raw) {
        float f = __expf(raw);                 // raw prefetched 8 steps ago: off-chain
        float c0 = 0.f, c1 = 0.f, c2 = 0.f, c3 = 0.f;
        float c4 = 0.f, c5 = 0.f, c6 = 0.f, c7 = 0.f;
        uint4 w;
        w = vb4[0];
        c0 = dot2acc(e0.x, w.x, c0); c1 = dot2acc(e0.y, w.y, c1);
        c2 = dot2acc(e0.z, w.z, c2); c3 = dot2acc(e0.w, w.w, c3);
        w = vb4[1];
        c4 = dot2acc(e1.x, w.x, c4); c5 = dot2acc(e1.y, w.y, c5);
        c6 = dot2acc(e1.z, w.z, c6); c7 = dot2acc(e1.w, w.w, c7);
        w = vb4[2];
        c0 = dot2acc(e2.x, w.x, c0); c1 = dot2acc(e2.y, w.y, c1);
        c2 = dot2acc(e2.z, w.z, c2); c3 = dot2acc(e2.w, w.w, c3);
        w = vb4[3];
        c4 = dot2acc(e3.x, w.x, c4); c5 = dot2acc(e3.y, w.y, c5);
        c6 = dot2acc(e3.z, w.z, c6); c7 = dot2acc(e3.w, w.w, c7);
        w = vb4[4];
        c0 = dot2acc(e4.x, w.x, c0); c1 = dot2acc(e4.y, w.y, c1);
        c2 = dot2acc(e4.z, w.z, c2); c3 = dot2acc(e4.w, w.w, c3);
        w = vb4[5];
        c4 = dot2acc(e5.x, w.x, c4); c5 = dot2acc(e5.y, w.y, c5);
        c6 = dot2acc(e5.z, w.z, c6); c7 = dot2acc(e5.w, w.w, c7);
        w = vb4[6];
        c0 = dot2acc(e6.x, w.x, c0); c1 = dot2acc(e6.y, w.y, c1);
        c2 = dot2acc(e6.z, w.z, c2); c3 = dot2acc(e6.w, w.w, c3);
        w = vb4[7];
        c4 = dot2acc(e7.x, w.x, c4); c5 = dot2acc(e7.y, w.y, c5);
        c6 = dot2acc(e7.z, w.z, c6); c7 = dot2acc(e7.w, w.w, c7);

        const float dot = ((c0 + c4) + (c1 + c5)) + ((c2 + c6) + (c3 + c7));
        float v = f * dot;                     // un-normalized new state (positive)

        // normalize: lane-0 value -> [2^-4, 2^-3); exact power-of-2, SALU-cheap
        unsigned bits = (unsigned)__builtin_amdgcn_readfirstlane((int)__float_as_uint(v));
        int e = (int)((bits >> 23) & 0xFF);    // biased exponent of lane-0 value
        float scale = __uint_as_float((unsigned)(250 - e) << 23);   // 2^(123-e)
        vn = v * scale;
        L += (float)(e - 123) * LN2;
        v_pk[lane] = __builtin_bit_cast(uint16_t, (_Float16)vn);
    };

    // ---- depth-8 prefetch in NAMED registers (no rotation -> counted vmcnt waits)
    float r0 = lg[NC * (1 < Tm1 ? 1 : Tm1) + lane];
    float r1 = lg[NC * (2 < Tm1 ? 2 : Tm1) + lane];
    float r2 = lg[NC * (3 < Tm1 ? 3 : Tm1) + lane];
    float r3 = lg[NC * (4 < Tm1 ? 4 : Tm1) + lane];
    float r4 = lg[NC * (5 < Tm1 ? 5 : Tm1) + lane];
    float r5 = lg[NC * (6 < Tm1 ? 6 : Tm1) + lane];
    float r6 = lg[NC * (7 < Tm1 ? 7 : Tm1) + lane];
    float r7 = lg[NC * (8 < Tm1 ? 8 : Tm1) + lane];

    int t = 1;
    for (; t + 8 <= len; t += 8) {             // steps t..t+7 all valid
        int p;
        step(r0); p = t +  8; p = p < Tm1 ? p : Tm1; r0 = lg[NC * p + lane];
        step(r1); p = t +  9; p = p < Tm1 ? p : Tm1; r1 = lg[NC * p + lane];
        step(r2); p = t + 10; p = p < Tm1 ? p : Tm1; r2 = lg[NC * p + lane];
        step(r3); p = t + 11; p = p < Tm1 ? p : Tm1; r3 = lg[NC * p + lane];
        step(r4); p = t + 12; p = p < Tm1 ? p : Tm1; r4 = lg[NC * p + lane];
        step(r5); p = t + 13; p = p < Tm1 ? p : Tm1; r5 = lg[NC * p + lane];
        step(r6); p = t + 14; p = p < Tm1 ? p : Tm1; r6 = lg[NC * p + lane];
        step(r7); p = t + 15; p = p < Tm1 ? p : Tm1; r7 = lg[NC * p + lane];
    }
    // remainder <= 7 steps, rows already prefetched in r0..r6
    if (t + 0 < len) step(r0);
    if (t + 1 < len) step(r1);
    if (t + 2 < len) step(r2);
    if (t + 3 < len) step(r3);
    if (t + 4 < len) step(r4);
    if (t + 5 < len) step(r5);
    if (t + 6 < len) step(r6);

    // ---- logZ = L + log(sum_i vn_i)
    const float logZ = L + __logf(wave_sum_bcast(vn));

    // ---- gold score (parallel, off critical path)
    const int* tg = tags + (size_t)n * T;
    float g = 0.f;
    for (int tt = 1 + lane; tt < len; tt += 64) {
        const int cur = tg[tt];
        const int prv = tg[tt - 1];
        g += trans[cur * NC + prv] + lg[tt * NC + cur];
    }
    g = wave_sum_bcast(g);

    if (lane == 0) {
        const int t0 = tg[0];
        const float gold = init_alphas[t0] + lg[t0] + g;
        out[n] = logZ - gold;
    }
}

extern "C" void kernel_launch(void* const* d_in, const int* in_sizes, int n_in,
                              void* d_out, int out_size, void* d_ws, size_t ws_size,
                              hipStream_t stream)
{
    const float* logits = (const float*)d_in[0];   // [N][T][C] f32
    const float* trans  = (const float*)d_in[1];   // [C][C]    f32
    const float* inita  = (const float*)d_in[2];   // [C]       f32
    const int*   lens   = (const int*)d_in[3];     // [N]       i32
    const int*   tags   = (const int*)d_in[4];     // [N][T]    i32
    float*       out    = (float*)d_out;           // [N]       f32

    const int N = 512, T = 1024;
    crf_nll_kernel<<<N, 64, 0, stream>>>(logits, trans, inita, lens, tags, out, N, T);
}

// Round 8
// 203.515 us; speedup vs baseline: 1.0371x; 1.0371x over previous
//
#include <hip/hip_runtime.h>
#include <cstdint>
#include <cstddef>

#define NC 64
#define LN2 0.6931471805599453f

typedef _Float16 half2_t __attribute__((ext_vector_type(2)));
typedef unsigned int uint32x4 __attribute__((ext_vector_type(4)));

static __device__ __forceinline__ float dot2acc(uint32_t a, uint32_t b, float c) {
#if __has_builtin(__builtin_amdgcn_fdot2)
    return __builtin_amdgcn_fdot2(__builtin_bit_cast(half2_t, a),
                                  __builtin_bit_cast(half2_t, b), c, false);
#else
    half2_t ha = __builtin_bit_cast(half2_t, a), hb = __builtin_bit_cast(half2_t, b);
    return c + (float)ha[0] * (float)hb[0] + (float)ha[1] * (float)hb[1];
#endif
}

template <int CTRL>
static __device__ __forceinline__ float dppf(float x) {
    return __int_as_float(__builtin_amdgcn_update_dpp(
        0, __float_as_int(x), CTRL, 0xf, 0xf, true));
}
static __device__ __forceinline__ float wave_sum_bcast(float x) {
    x = x + dppf<0x111>(x);
    x = x + dppf<0x112>(x);
    x = x + dppf<0x114>(x);
    x = x + dppf<0x118>(x);
    x = x + dppf<0x142>(x);   // row_bcast15
    x = x + dppf<0x143>(x);   // row_bcast31
    return __int_as_float(__builtin_amdgcn_readlane(__float_as_int(x), 63));
}

__global__ __launch_bounds__(64, 1)
void crf_nll_kernel(const float* __restrict__ logits,
                    const float* __restrict__ trans,
                    const float* __restrict__ init_alphas,
                    const int*  __restrict__ lengths,
                    const int*  __restrict__ tags,
                    float* __restrict__ out,
                    int N, int T)
{
    const int n = blockIdx.x;
    const int lane = threadIdx.x;              // 0..63, owns class row `lane`
    const float* lg = logits + (size_t)n * T * NC;
    const int len = lengths[n];                // in [2, T]
    const int Tm1 = T - 1;

    __shared__ __align__(16) uint32_t E_pk[64 * 32];    // exp(trans) f16x2, row-major
    __shared__ __align__(16) uint16_t v_pk[NC + 8];     // state, packed f16

    // ---- fill packed E in LDS: word i = {f16(e^tr[2i]), f16(e^tr[2i+1])} (row-major)
    const float2* tr2 = reinterpret_cast<const float2*>(trans);
    #pragma unroll
    for (int i = lane; i < 64 * 32; i += 64) {
        float2 t2 = tr2[i];
        uint32_t lo = (uint32_t)__builtin_bit_cast(uint16_t, (_Float16)__expf(t2.x));
        uint32_t hi = (uint32_t)__builtin_bit_cast(uint16_t, (_Float16)__expf(t2.y));
        E_pk[i] = (hi << 16) | lo;
    }

    // ---- hoist this lane's E row (128 B) into 8 vec4 registers via inline asm.
    // Asm outputs are NOT rematerializable -> allocator must keep them resident
    // across the loop (this is what rounds 5-7's C++ loads failed to achieve).
    uint32x4 e0, e1, e2, e3, e4, e5, e6, e7;
    {
        uint32_t e_addr = (uint32_t)(uintptr_t)&E_pk[0] + (uint32_t)(lane * 128);
        asm volatile(
            "ds_read_b128 %0, %8 offset:0\n\t"
            "ds_read_b128 %1, %8 offset:16\n\t"
            "ds_read_b128 %2, %8 offset:32\n\t"
            "ds_read_b128 %3, %8 offset:48\n\t"
            "ds_read_b128 %4, %8 offset:64\n\t"
            "ds_read_b128 %5, %8 offset:80\n\t"
            "ds_read_b128 %6, %8 offset:96\n\t"
            "ds_read_b128 %7, %8 offset:112\n\t"
            "s_waitcnt lgkmcnt(0)"
            : "=&v"(e0), "=&v"(e1), "=&v"(e2), "=&v"(e3),
              "=&v"(e4), "=&v"(e5), "=&v"(e6), "=&v"(e7)
            : "v"(e_addr)
            : "memory");
        __builtin_amdgcn_sched_barrier(0);     // rule 18: fence reg-only reordering
    }

    // ---- init: alpha0 = init + logits[0]; seed with lane-0-anchored offset
    float a0 = init_alphas[lane] + lg[lane];
    float L  = __int_as_float(__builtin_amdgcn_readfirstlane(__float_as_int(a0)))
               + 8.f * LN2;                    // lane0 value = e^-8 (~2^-11.5)
    float vn = __expf(a0 - L);
    v_pk[lane] = __builtin_bit_cast(uint16_t, (_Float16)vn);
    // single wave: DS pipe is in-order; no barrier needed anywhere

    const uint32x4* vb4 = reinterpret_cast<const uint32x4*>(v_pk);

    // Lagged normalization: scale s (exact power of 2) computed from step t's
    // lane-0 value is APPLIED at step t+1 (folded into f*s, off the chain).
    // Invariant: alpha = log(w_lds) + L, maintained exactly (s is 2^k).
    float s_cur = 1.0f;    // scale to apply this step
    float dL    = 0.0f;    // -log(s_cur), added to L when s_cur is applied

    auto step = [&](float raw) {
        float fs = __expf(raw) * s_cur;        // raw prefetched 8 steps ago: off-chain
        L += dL;
        float c0 = 0.f, c1 = 0.f, c2 = 0.f, c3 = 0.f;
        float c4 = 0.f, c5 = 0.f, c6 = 0.f, c7 = 0.f;
        uint32x4 w;
        w = vb4[0];
        c0 = dot2acc(e0.x, w.x, c0); c1 = dot2acc(e0.y, w.y, c1);
        c2 = dot2acc(e0.z, w.z, c2); c3 = dot2acc(e0.w, w.w, c3);
        w = vb4[1];
        c4 = dot2acc(e1.x, w.x, c4); c5 = dot2acc(e1.y, w.y, c5);
        c6 = dot2acc(e1.z, w.z, c6); c7 = dot2acc(e1.w, w.w, c7);
        w = vb4[2];
        c0 = dot2acc(e2.x, w.x, c0); c1 = dot2acc(e2.y, w.y, c1);
        c2 = dot2acc(e2.z, w.z, c2); c3 = dot2acc(e2.w, w.w, c3);
        w = vb4[3];
        c4 = dot2acc(e3.x, w.x, c4); c5 = dot2acc(e3.y, w.y, c5);
        c6 = dot2acc(e3.z, w.z, c6); c7 = dot2acc(e3.w, w.w, c7);
        w = vb4[4];
        c0 = dot2acc(e4.x, w.x, c0); c1 = dot2acc(e4.y, w.y, c1);
        c2 = dot2acc(e4.z, w.z, c2); c3 = dot2acc(e4.w, w.w, c3);
        w = vb4[5];
        c4 = dot2acc(e5.x, w.x, c4); c5 = dot2acc(e5.y, w.y, c5);
        c6 = dot2acc(e5.z, w.z, c6); c7 = dot2acc(e5.w, w.w, c7);
        w = vb4[6];
        c0 = dot2acc(e6.x, w.x, c0); c1 = dot2acc(e6.y, w.y, c1);
        c2 = dot2acc(e6.z, w.z, c2); c3 = dot2acc(e6.w, w.w, c3);
        w = vb4[7];
        c4 = dot2acc(e7.x, w.x, c4); c5 = dot2acc(e7.y, w.y, c5);
        c6 = dot2acc(e7.z, w.z, c6); c7 = dot2acc(e7.w, w.w, c7);

        const float dot = ((c0 + c4) + (c1 + c5)) + ((c2 + c6) + (c3 + c7));
        float v = fs * dot;                    // new state (positive)
        vn = v;
        v_pk[lane] = __builtin_bit_cast(uint16_t, (_Float16)v);   // chain ends here

        // off-chain: derive next step's scale from lane-0 exponent (exact 2^k)
        unsigned bits = (unsigned)__builtin_amdgcn_readfirstlane((int)__float_as_uint(v));
        int e = (int)((bits >> 23) & 0xFF);
        s_cur = __uint_as_float((unsigned)(246 - e) << 23);       // 2^(119-e)
        dL    = (float)(e - 119) * LN2;
    };

    // ---- depth-8 prefetch in NAMED registers (counted vmcnt waits)
    float r0 = lg[NC * (1 < Tm1 ? 1 : Tm1) + lane];
    float r1 = lg[NC * (2 < Tm1 ? 2 : Tm1) + lane];
    float r2 = lg[NC * (3 < Tm1 ? 3 : Tm1) + lane];
    float r3 = lg[NC * (4 < Tm1 ? 4 : Tm1) + lane];
    float r4 = lg[NC * (5 < Tm1 ? 5 : Tm1) + lane];
    float r5 = lg[NC * (6 < Tm1 ? 6 : Tm1) + lane];
    float r6 = lg[NC * (7 < Tm1 ? 7 : Tm1) + lane];
    float r7 = lg[NC * (8 < Tm1 ? 8 : Tm1) + lane];

    int t = 1;
    for (; t + 8 <= len; t += 8) {             // steps t..t+7 all valid
        int p;
        step(r0); p = t +  8; p = p < Tm1 ? p : Tm1; r0 = lg[NC * p + lane];
        step(r1); p = t +  9; p = p < Tm1 ? p : Tm1; r1 = lg[NC * p + lane];
        step(r2); p = t + 10; p = p < Tm1 ? p : Tm1; r2 = lg[NC * p + lane];
        step(r3); p = t + 11; p = p < Tm1 ? p : Tm1; r3 = lg[NC * p + lane];
        step(r4); p = t + 12; p = p < Tm1 ? p : Tm1; r4 = lg[NC * p + lane];
        step(r5); p = t + 13; p = p < Tm1 ? p : Tm1; r5 = lg[NC * p + lane];
        step(r6); p = t + 14; p = p < Tm1 ? p : Tm1; r6 = lg[NC * p + lane];
        step(r7); p = t + 15; p = p < Tm1 ? p : Tm1; r7 = lg[NC * p + lane];
    }
    // remainder <= 7 steps, rows already prefetched in r0..r6
    if (t + 0 < len) step(r0);
    if (t + 1 < len) step(r1);
    if (t + 2 < len) step(r2);
    if (t + 3 < len) step(r3);
    if (t + 4 < len) step(r4);
    if (t + 5 < len) step(r5);
    if (t + 6 < len) step(r6);

    // ---- logZ = L + log(sum_i vn_i)   (final unapplied s_cur/dL correctly excluded)
    const float logZ = L + __logf(wave_sum_bcast(vn));

    // ---- gold score (parallel, off critical path)
    const int* tg = tags + (size_t)n * T;
    float g = 0.f;
    for (int tt = 1 + lane; tt < len; tt += 64) {
        const int cur = tg[tt];
        const int prv = tg[tt - 1];
        g += trans[cur * NC + prv] + lg[tt * NC + cur];
    }
    g = wave_sum_bcast(g);

    if (lane == 0) {
        const int t0 = tg[0];
        const float gold = init_alphas[t0] + lg[t0] + g;
        out[n] = logZ - gold;
    }
}

extern "C" void kernel_launch(void* const* d_in, const int* in_sizes, int n_in,
                              void* d_out, int out_size, void* d_ws, size_t ws_size,
                              hipStream_t stream)
{
    const float* logits = (const float*)d_in[0];   // [N][T][C] f32
    const float* trans  = (const float*)d_in[1];   // [C][C]    f32
    const float* inita  = (const float*)d_in[2];   // [C]       f32
    const int*   lens   = (const int*)d_in[3];     // [N]       i32
    const int*   tags   = (const int*)d_in[4];     // [N][T]    i32
    float*       out    = (float*)d_out;           // [N]       f32

    const int N = 512, T = 1024;
    crf_nll_kernel<<<N, 64, 0, stream>>>(logits, trans, inita, lens, tags, out, N, T);
}